// Round 2
// baseline (159.221 us; speedup 1.0000x reference)
//
#include <hip/hip_runtime.h>

#define STEP 100
#define NGUESS 256
#define CPG 20   // chunks per rank-block

// AES inverse S-box: INV_SBOX[SBOX[x]] == x
__device__ __constant__ int INV_SBOXD[256] = {
   82,   9, 106, 213,  48,  54, 165,  56, 191,  64, 163, 158, 129, 243, 215, 251,
  124, 227,  57, 130, 155,  47, 255, 135,  52, 142,  67,  68, 196, 222, 233, 203,
   84, 123, 148,  50, 166, 194,  35,  61, 238,  76, 149,  11,  66, 250, 195,  78,
    8,  46, 161, 102,  40, 217,  36, 178, 118,  91, 162,  73, 109, 139, 209,  37,
  114, 248, 246, 100, 134, 104, 152,  22, 212, 164,  92, 204,  93, 101, 182, 146,
  108, 112,  72,  80, 253, 237, 185, 218,  94,  21,  70,  87, 167, 141, 157, 132,
  144, 216, 171,   0, 140, 188, 211,  10, 247, 228,  88,   5, 184, 179,  69,   6,
  208,  44,  30, 143, 202,  63,  15,   2, 193, 175, 189,   3,   1,  19, 138, 107,
   58, 145,  17,  65,  79, 103, 220, 234, 151, 242, 207, 206, 240, 180, 230, 115,
  150, 172, 116,  34, 231, 173,  53, 133, 226, 249,  55, 232,  28, 117, 223, 110,
   71, 241,  26, 113,  29,  41, 197, 137, 111, 183,  98,  14, 170,  24, 190,  27,
  252,  86,  62,  75, 198, 210, 121,  32, 154, 219, 192, 254, 120, 205,  90, 244,
   31, 221, 168,  51, 136,   7, 199,  49, 177,  18,  16,  89,  39, 128, 236,  95,
   96,  81, 127, 169,  25, 181,  74,  13,  45, 229, 122, 159, 147, 201, 156, 239,
  160, 224,  59,  77, 174,  42, 245, 176, 200, 235, 187,  60, 131,  83, 153,  97,
   23,  43,   4, 126, 186, 119, 214,  38, 225, 105,  20,  99,  85,  33,  12, 125
};

// K1 (scatter form, barrier-free inner loop):
// element (r,c) contributes log(pred[r][c]) to guess g = meta[r] ^ inv_sbox[c].
// One block per chunk; wave w owns rows {w, w+4, ...} and its own LDS
// accumulator slice accw[w][256] (no cross-wave races, deterministic).
// Lane l owns columns 4l..4l+3, so its inv_sbox values are registers.
__global__ __launch_bounds__(256) void k_chunksums(const float* __restrict__ pred,
                                                   const int* __restrict__ meta,
                                                   float* __restrict__ cs) {
  __shared__ float accw[4][NGUESS];
  __shared__ int smeta[STEP];
  const int tid = threadIdx.x;
  const int w = tid >> 6;        // wave id
  const int l = tid & 63;        // lane id
  const int c0 = l << 2;         // this lane's first column
  const int chunk = blockIdx.x;
  const long base = (long)chunk * STEP;

  // zero this wave's accumulator slice (each lane zeroes its 4 slots)
  accw[w][c0 + 0] = 0.f;
  accw[w][c0 + 1] = 0.f;
  accw[w][c0 + 2] = 0.f;
  accw[w][c0 + 3] = 0.f;
  if (tid < STEP) smeta[tid] = meta[base + tid];

  const int inv0 = INV_SBOXD[c0 + 0];
  const int inv1 = INV_SBOXD[c0 + 1];
  const int inv2 = INV_SBOXD[c0 + 2];
  const int inv3 = INV_SBOXD[c0 + 3];
  __syncthreads();   // smeta ready (accw slices are wave-private)

  // prefetch-1 pipelined row loop: 25 rows per wave
  float4 v = *reinterpret_cast<const float4*>(pred + ((base + w) << 8) + c0);
  for (int r = w; r < STEP; ) {
    const int m = smeta[r];
    r += 4;
    float4 nv;
    if (r < STEP)
      nv = *reinterpret_cast<const float4*>(pred + ((base + r) << 8) + c0);
    const float l0 = (v.x != 0.f) ? logf(v.x) : 0.f;
    const float l1 = (v.y != 0.f) ? logf(v.y) : 0.f;
    const float l2 = (v.z != 0.f) ? logf(v.z) : 0.f;
    const float l3 = (v.w != 0.f) ? logf(v.w) : 0.f;
    // targets m^inv* are distinct within the row; wave-private slice ->
    // ds_add_f32, ordered per-wave, deterministic.
    atomicAdd(&accw[w][m ^ inv0], l0);
    atomicAdd(&accw[w][m ^ inv1], l1);
    atomicAdd(&accw[w][m ^ inv2], l2);
    atomicAdd(&accw[w][m ^ inv3], l3);
    v = nv;
  }

  __syncthreads();
  cs[chunk * NGUESS + tid] =
      accw[0][tid] + accw[1][tid] + accw[2][tid] + accw[3][tid];
}

// K2a: per-group (20-chunk) sums in double, for fast prefix derivation.
__global__ __launch_bounds__(256) void k_groupsum(const float* __restrict__ cs,
                                                  double* __restrict__ gsum) {
  const int b = blockIdx.x, g = threadIdx.x;
  double s = 0.0;
#pragma unroll
  for (int c = 0; c < CPG; ++c) s += (double)cs[(b * CPG + c) * NGUESS + g];
  gsum[b * NGUESS + g] = s;
}

// K2c: each block handles 20 chunks; derives its cumsum prefix from group
// sums, then per chunk computes rank = #(score > key_score) via ballot.
__global__ __launch_bounds__(256) void k_ranks(const float* __restrict__ cs,
                                               const double* __restrict__ gsum,
                                               const int* __restrict__ ckp,
                                               int* __restrict__ outRanks,
                                               int* __restrict__ outX) {
  const int b = blockIdx.x, g = threadIdx.x;
  const int ck = *ckp;
  double acc = 0.0;
  for (int bb = 0; bb < b; ++bb) acc += gsum[bb * NGUESS + g];
  __shared__ double keysh;
  __shared__ int cnt;
  for (int c = 0; c < CPG; ++c) {
    const int chunk = b * CPG + c;
    acc += (double)cs[chunk * NGUESS + g];
    if (g == ck) keysh = acc;
    if (g == 0) cnt = 0;
    __syncthreads();
    const int p = (acc > keysh) ? 1 : 0;
    const unsigned long long m = __ballot(p);
    if ((g & 63) == 0) atomicAdd(&cnt, (int)__popcll(m));
    __syncthreads();
    if (g == 0) outRanks[chunk] = cnt;
  }
  if (g < CPG) {
    const int chunk = b * CPG + g;
    outX[chunk] = (chunk + 1) * STEP;
  }
}

extern "C" void kernel_launch(void* const* d_in, const int* in_sizes, int n_in,
                              void* d_out, int out_size, void* d_ws, size_t ws_size,
                              hipStream_t stream) {
  const float* pred = (const float*)d_in[0];
  const int* meta   = (const int*)d_in[1];
  // d_in[2] = guess_range (256), d_in[3] = correct_key (34), d_in[4] = step (100)
  const int* ckp    = (const int*)d_in[3];

  const int N = in_sizes[1];            // 100000
  const int num_chunks = N / STEP;      // 1000
  const int ngroups = num_chunks / CPG; // 50

  float*  cs   = (float*)d_ws;                                         // [1000][256] f32
  double* gsum = (double*)((char*)d_ws +
                           (size_t)num_chunks * NGUESS * sizeof(float)); // [50][256] f64

  int* out = (int*)d_out;               // ranks[0..nc), x_rank[nc..2nc)

  k_chunksums<<<num_chunks, 256, 0, stream>>>(pred, meta, cs);
  k_groupsum <<<ngroups,   256, 0, stream>>>(cs, gsum);
  k_ranks    <<<ngroups,   256, 0, stream>>>(cs, gsum, ckp, out, out + num_chunks);
}

// Round 3
// 45.326 us; speedup vs baseline: 3.5128x; 3.5128x over previous
//
#include <hip/hip_runtime.h>

#define STEP 100
#define NGUESS 256
#define CPG 20   // chunks per rank-block

__device__ __constant__ int SBOXD[256] = {
  99, 124, 119, 123, 242, 107, 111, 197, 48, 1, 103, 43, 254, 215, 171, 118,
  202, 130, 201, 125, 250, 89, 71, 240, 173, 212, 162, 175, 156, 164, 114, 192,
  183, 253, 147, 38, 54, 63, 247, 204, 52, 165, 229, 241, 113, 216, 49, 21,
  4, 199, 35, 195, 24, 150, 5, 154, 7, 18, 128, 226, 235, 39, 178, 117,
  9, 131, 44, 26, 27, 110, 90, 160, 82, 59, 214, 179, 41, 227, 47, 132,
  83, 209, 0, 237, 32, 252, 177, 91, 106, 203, 190, 57, 74, 76, 88, 207,
  208, 239, 170, 251, 67, 77, 51, 133, 69, 249, 2, 127, 80, 60, 159, 168,
  81, 163, 64, 143, 146, 157, 56, 245, 188, 182, 218, 33, 16, 255, 243, 210,
  205, 12, 19, 236, 95, 151, 68, 23, 196, 167, 126, 61, 100, 93, 25, 115,
  96, 129, 79, 220, 34, 42, 144, 136, 70, 238, 184, 20, 222, 94, 11, 219,
  224, 50, 58, 10, 73, 6, 36, 92, 194, 211, 172, 98, 145, 149, 228, 121,
  231, 200, 55, 109, 141, 213, 78, 169, 108, 86, 244, 234, 101, 122, 174, 8,
  186, 120, 37, 46, 28, 166, 180, 198, 232, 221, 116, 31, 75, 189, 139, 138,
  112, 62, 181, 102, 72, 3, 246, 14, 97, 53, 87, 185, 134, 193, 29, 158,
  225, 248, 152, 17, 105, 217, 142, 148, 155, 30, 135, 233, 206, 85, 40, 223,
  140, 161, 137, 13, 191, 230, 66, 104, 65, 153, 45, 15, 176, 84, 187, 22
};

// wave-level 1KB DMA: 64 lanes x 16B. gsrc = per-lane address; ldst = wave-uniform.
__device__ __forceinline__ void gload1k(const float* gsrc, float* ldst) {
  __builtin_amdgcn_global_load_lds(
      (const __attribute__((address_space(1))) unsigned int*)gsrc,
      (__attribute__((address_space(3))) unsigned int*)ldst, 16, 0, 0);
}

// K1 (gather form, pipelined): one block per 100x256 chunk.
// Tiles of 8 rows (8KB) triple-buffered in LDS via global_load_lds(16B),
// counted vmcnt(2) (tile t+1 stays in flight while gathering tile t),
// one raw s_barrier per tile. Thread g gathers lrow[k][sbox[meta^g]].
__global__ __launch_bounds__(256) void k_chunksums(const float* __restrict__ pred,
                                                   const int* __restrict__ meta,
                                                   float* __restrict__ cs) {
  __shared__ float buf[3][8][NGUESS];   // 24 KB
  __shared__ int sboxs[NGUESS];
  __shared__ int smeta[STEP];

  const int tid  = threadIdx.x;
  const int w    = tid >> 6;
  const int lane = tid & 63;
  const int g    = tid;
  const int chunk = blockIdx.x;
  const size_t base = (size_t)chunk * STEP;

  sboxs[tid] = SBOXD[tid];
  if (tid < STEP) smeta[tid] = meta[base + tid];
  __syncthreads();   // tables ready (drains vmcnt too — before any pipeline loads)

  // full tile t: rows t*8 .. t*8+7; wave w DMAs rows 2w, 2w+1
  auto issue_full = [&](int t) {
    const float* src = pred + ((base + (size_t)t * 8) << 8);
    float* dst = &buf[t % 3][0][0];
    const int j0 = w * 2, j1 = j0 + 1;
    gload1k(src + (size_t)j0 * NGUESS + lane * 4, dst + j0 * NGUESS);
    gload1k(src + (size_t)j1 * NGUESS + lane * 4, dst + j1 * NGUESS);
  };
  // tail tile 12: rows 96..99; wave w DMAs row w
  auto issue_tail = [&]() {
    const float* src = pred + ((base + 96) << 8);
    gload1k(src + (size_t)w * NGUESS + lane * 4, &buf[0][w][0]);
  };

  float acc = 0.f;
  auto gather = [&](int t, int nrows) {
    const float (*lb)[NGUESS] = buf[t % 3];
#pragma unroll
    for (int k = 0; k < 8; ++k) {
      if (k >= nrows) break;
      const int m = smeta[t * 8 + k];           // wave-uniform broadcast
      const float v = lb[k][sboxs[m ^ g]];
      acc += (v != 0.f) ? __logf(v) : 0.f;
    }
  };

  issue_full(0);
  issue_full(1);
  for (int t = 0; t < 10; ++t) {
    asm volatile("s_waitcnt vmcnt(2) lgkmcnt(0)" ::: "memory");
    __builtin_amdgcn_s_barrier();
    issue_full(t + 2);
    gather(t, 8);
  }
  // t = 10: issue tail (1 load/wave)
  asm volatile("s_waitcnt vmcnt(2) lgkmcnt(0)" ::: "memory");
  __builtin_amdgcn_s_barrier();
  issue_tail();
  gather(10, 8);
  // t = 11
  asm volatile("s_waitcnt vmcnt(1) lgkmcnt(0)" ::: "memory");
  __builtin_amdgcn_s_barrier();
  gather(11, 8);
  // t = 12 (4 rows)
  asm volatile("s_waitcnt vmcnt(0) lgkmcnt(0)" ::: "memory");
  __builtin_amdgcn_s_barrier();
  gather(12, 4);

  cs[chunk * NGUESS + g] = acc;
}

// K2a: per-group (20-chunk) sums in double, for fast prefix derivation.
__global__ __launch_bounds__(256) void k_groupsum(const float* __restrict__ cs,
                                                  double* __restrict__ gsum) {
  const int b = blockIdx.x, g = threadIdx.x;
  double s = 0.0;
#pragma unroll
  for (int c = 0; c < CPG; ++c) s += (double)cs[(b * CPG + c) * NGUESS + g];
  gsum[b * NGUESS + g] = s;
}

// K2c: each block handles 20 chunks; derives its cumsum prefix from group
// sums, then per chunk computes rank = #(score > key_score) via ballot.
__global__ __launch_bounds__(256) void k_ranks(const float* __restrict__ cs,
                                               const double* __restrict__ gsum,
                                               const int* __restrict__ ckp,
                                               int* __restrict__ outRanks,
                                               int* __restrict__ outX) {
  const int b = blockIdx.x, g = threadIdx.x;
  const int ck = *ckp;
  double acc = 0.0;
  for (int bb = 0; bb < b; ++bb) acc += gsum[bb * NGUESS + g];
  __shared__ double keysh;
  __shared__ int cnt;
  for (int c = 0; c < CPG; ++c) {
    const int chunk = b * CPG + c;
    acc += (double)cs[chunk * NGUESS + g];
    if (g == ck) keysh = acc;
    if (g == 0) cnt = 0;
    __syncthreads();
    const int p = (acc > keysh) ? 1 : 0;
    const unsigned long long m = __ballot(p);
    if ((g & 63) == 0) atomicAdd(&cnt, (int)__popcll(m));
    __syncthreads();
    if (g == 0) outRanks[chunk] = cnt;
  }
  if (g < CPG) {
    const int chunk = b * CPG + g;
    outX[chunk] = (chunk + 1) * STEP;
  }
}

extern "C" void kernel_launch(void* const* d_in, const int* in_sizes, int n_in,
                              void* d_out, int out_size, void* d_ws, size_t ws_size,
                              hipStream_t stream) {
  const float* pred = (const float*)d_in[0];
  const int* meta   = (const int*)d_in[1];
  // d_in[2] = guess_range (256), d_in[3] = correct_key (34), d_in[4] = step (100)
  const int* ckp    = (const int*)d_in[3];

  const int N = in_sizes[1];            // 100000
  const int num_chunks = N / STEP;      // 1000
  const int ngroups = num_chunks / CPG; // 50

  float*  cs   = (float*)d_ws;                                           // [1000][256] f32
  double* gsum = (double*)((char*)d_ws +
                           (size_t)num_chunks * NGUESS * sizeof(float)); // [50][256] f64

  int* out = (int*)d_out;               // ranks[0..nc), x_rank[nc..2nc)

  k_chunksums<<<num_chunks, 256, 0, stream>>>(pred, meta, cs);
  k_groupsum <<<ngroups,   256, 0, stream>>>(cs, gsum);
  k_ranks    <<<ngroups,   256, 0, stream>>>(cs, gsum, ckp, out, out + num_chunks);
}

// Round 4
// 43.180 us; speedup vs baseline: 3.6874x; 1.0497x over previous
//
#include <hip/hip_runtime.h>

#define STEP 100
#define NGUESS 256
#define CPG 20   // chunks per group

// AES inverse S-box: INV_SBOX[SBOX[x]] == x
__device__ __constant__ int INV_SBOXD[256] = {
   82,   9, 106, 213,  48,  54, 165,  56, 191,  64, 163, 158, 129, 243, 215, 251,
  124, 227,  57, 130, 155,  47, 255, 135,  52, 142,  67,  68, 196, 222, 233, 203,
   84, 123, 148,  50, 166, 194,  35,  61, 238,  76, 149,  11,  66, 250, 195,  78,
    8,  46, 161, 102,  40, 217,  36, 178, 118,  91, 162,  73, 109, 139, 209,  37,
  114, 248, 246, 100, 134, 104, 152,  22, 212, 164,  92, 204,  93, 101, 182, 146,
  108, 112,  72,  80, 253, 237, 185, 218,  94,  21,  70,  87, 167, 141, 157, 132,
  144, 216, 171,   0, 140, 188, 211,  10, 247, 228,  88,   5, 184, 179,  69,   6,
  208,  44,  30, 143, 202,  63,  15,   2, 193, 175, 189,   3,   1,  19, 138, 107,
   58, 145,  17,  65,  79, 103, 220, 234, 151, 242, 207, 206, 240, 180, 230, 115,
  150, 172, 116,  34, 231, 173,  53, 133, 226, 249,  55, 232,  28, 117, 223, 110,
   71, 241,  26, 113,  29,  41, 197, 137, 111, 183,  98,  14, 170,  24, 190,  27,
  252,  86,  62,  75, 198, 210, 121,  32, 154, 219, 192, 254, 120, 205,  90, 244,
   31, 221, 168,  51, 136,   7, 199,  49, 177,  18,  16,  89,  39, 128, 236,  95,
   96,  81, 127, 169,  25, 181,  74,  13,  45, 229, 122, 159, 147, 201, 156, 239,
  160, 224,  59,  77, 174,  42, 245, 176, 200, 235, 187,  60, 131,  83, 153,  97,
   23,  43,   4, 126, 186, 119, 214,  38, 225, 105,  20,  99,  85,  33,  12, 125
};

// K1: one block per 100x256 chunk; wave w privately owns rows [25w, 25w+25).
// Per row: coalesced float4 load -> 4 logs -> scatter into wave-private LDS
// ring slot at inv_sbox[col] (so slot[p] = log(row[sbox[p]])) -> gather guess
// j*64+l as slot[m ^ (j*64+l)] (bank-conflict-free across the wave).
// No barriers in the loop; TLP + unroll-4 hide all latency.
__global__ __launch_bounds__(256) void k_chunksums(const float* __restrict__ pred,
                                                   const int* __restrict__ meta,
                                                   float* __restrict__ cs) {
  __shared__ float prow[4][4][NGUESS];  // [wave][ring][perm-log-row] 16 KB
  __shared__ float red[4][NGUESS];      // cross-wave reduce 4 KB
  __shared__ int smeta[STEP];

  const int tid = threadIdx.x;
  const int w = tid >> 6;
  const int l = tid & 63;
  const int chunk = blockIdx.x;
  const size_t base = (size_t)chunk * STEP;

  if (tid < STEP) smeta[tid] = meta[base + tid];
  const int c0 = l << 2;
  const int t0 = INV_SBOXD[c0 + 0];
  const int t1 = INV_SBOXD[c0 + 1];
  const int t2 = INV_SBOXD[c0 + 2];
  const int t3 = INV_SBOXD[c0 + 3];
  __syncthreads();  // smeta ready

  float a0 = 0.f, a1 = 0.f, a2 = 0.f, a3 = 0.f;  // guesses l, 64+l, 128+l, 192+l
  const int r0 = w * 25;
#pragma unroll 4
  for (int i = 0; i < 25; ++i) {
    const int r = r0 + i;
    const float4 v = *reinterpret_cast<const float4*>(pred + ((base + r) << 8) + c0);
    const int m = smeta[r];
    float* slot = prow[w][i & 3];
    slot[t0] = (v.x != 0.f) ? __logf(v.x) : 0.f;
    slot[t1] = (v.y != 0.f) ? __logf(v.y) : 0.f;
    slot[t2] = (v.z != 0.f) ? __logf(v.z) : 0.f;
    slot[t3] = (v.w != 0.f) ? __logf(v.w) : 0.f;
    const int mx = m ^ l;            // bank = mx & 31: each bank hit exactly 2x/wave
    a0 += slot[mx];
    a1 += slot[mx ^ 64];
    a2 += slot[mx ^ 128];
    a3 += slot[mx ^ 192];
  }

  red[w][l]       = a0;
  red[w][l + 64]  = a1;
  red[w][l + 128] = a2;
  red[w][l + 192] = a3;
  __syncthreads();
  cs[chunk * NGUESS + tid] =
      red[0][tid] + red[1][tid] + red[2][tid] + red[3][tid];
}

// K2a: per-group (20-chunk) sums in double.
__global__ __launch_bounds__(256) void k_groupsum(const float* __restrict__ cs,
                                                  double* __restrict__ gsum) {
  const int b = blockIdx.x, g = threadIdx.x;
  double s = 0.0;
#pragma unroll
  for (int c = 0; c < CPG; ++c) s += (double)cs[(b * CPG + c) * NGUESS + g];
  gsum[b * NGUESS + g] = s;
}

// K2b: one block per chunk. acc_g = sum(full-group sums) + sum(partial chunk
// rows) in double; rank = popcount(acc > acc[ck]) via ballot. All loads
// independent & coalesced; no serial chunk loop.
__global__ __launch_bounds__(256) void k_ranks(const float* __restrict__ cs,
                                               const double* __restrict__ gsum,
                                               const int* __restrict__ ckp,
                                               int* __restrict__ outRanks,
                                               int* __restrict__ outX) {
  const int c = blockIdx.x;       // chunk id
  const int g = threadIdx.x;
  const int grp = c / CPG;
  double acc = 0.0;
  for (int bb = 0; bb < grp; ++bb) acc += gsum[bb * NGUESS + g];
  for (int cc = grp * CPG; cc <= c; ++cc) acc += (double)cs[cc * NGUESS + g];

  __shared__ double keysh;
  __shared__ int cnt;
  const int ck = *ckp;
  if (g == ck) keysh = acc;
  if (g == 0) cnt = 0;
  __syncthreads();
  const unsigned long long mball = __ballot(acc > keysh);
  if ((g & 63) == 0) atomicAdd(&cnt, (int)__popcll(mball));
  __syncthreads();
  if (g == 0) {
    outRanks[c] = cnt;
    outX[c] = (c + 1) * STEP;
  }
}

extern "C" void kernel_launch(void* const* d_in, const int* in_sizes, int n_in,
                              void* d_out, int out_size, void* d_ws, size_t ws_size,
                              hipStream_t stream) {
  const float* pred = (const float*)d_in[0];
  const int* meta   = (const int*)d_in[1];
  // d_in[2] = guess_range (256), d_in[3] = correct_key (34), d_in[4] = step (100)
  const int* ckp    = (const int*)d_in[3];

  const int N = in_sizes[1];            // 100000
  const int num_chunks = N / STEP;      // 1000
  const int ngroups = num_chunks / CPG; // 50

  float*  cs   = (float*)d_ws;                                           // [1000][256] f32
  double* gsum = (double*)((char*)d_ws +
                           (size_t)num_chunks * NGUESS * sizeof(float)); // [50][256] f64

  int* out = (int*)d_out;               // ranks[0..nc), x_rank[nc..2nc)

  k_chunksums<<<num_chunks, 256, 0, stream>>>(pred, meta, cs);
  k_groupsum <<<ngroups,    256, 0, stream>>>(cs, gsum);
  k_ranks    <<<num_chunks, 256, 0, stream>>>(cs, gsum, ckp, out, out + num_chunks);
}